// Round 1
// baseline (1474.083 us; speedup 1.0000x reference)
//
#include <hip/hip_runtime.h>
#include <stdint.h>

#define BN_EPS 1e-3f

constexpr int B = 32, H = 56, W = 56, C = 256;
constexpr int WPC = 8;            // u32 words per 256-channel bit vector
constexpr int PW = W + 2;         // padded width (58)
constexpr int XROW = PW * WPC;    // 464 u32 per padded row
constexpr int HO = 28, WO = 28;   // pooled output dims
constexpr int NW = 72;            // 9 taps * 8 words per output channel

// ---------------------------------------------------------------------------
// Binarize x: bit c = (x >= 0). 256 threads = one pixel's 256 channels.
// Pack via wave ballot: lane i of wave w -> channel w*64+i -> u64 word pix*4+w.
__global__ __launch_bounds__(256) void k_binarize_x(const float* __restrict__ x,
                                                    uint32_t* __restrict__ xbits) {
  int i = blockIdx.x * 256 + threadIdx.x;
  float v = x[i];
  unsigned long long m = __ballot(v >= 0.0f);
  if ((threadIdx.x & 63) == 0) {
    ((unsigned long long*)xbits)[i >> 6] = m;
  }
}

// ---------------------------------------------------------------------------
// Binarize weights HWIO [3][3][256 ic][256 oc] -> wbT[j][oc], j = tap*8+word,
// bit b of word = ic = word*32+b.
__global__ __launch_bounds__(256) void k_binarize_w(const float* __restrict__ w,
                                                    uint32_t* __restrict__ wbT) {
  int j = blockIdx.x;        // 0..71
  int oc = threadIdx.x;      // 0..255
  int tap = j >> 3, ww = j & 7;
  const float* base = w + ((size_t)(tap * C) + ww * 32) * C + oc;
  uint32_t bits = 0;
#pragma unroll
  for (int b = 0; b < 32; ++b) {
    float v = base[(size_t)b * C];
    bits |= (v >= 0.0f ? 1u : 0u) << b;
  }
  wbT[j * C + oc] = bits;
}

// ---------------------------------------------------------------------------
// Stage NROWS bit rows (with 1-pixel zero border on all sides) into LDS.
template <int NROWS>
__device__ __forceinline__ void stage_rows(const uint32_t* __restrict__ bits, int b,
                                           int rtop, uint32_t* xl) {
  for (int row = 0; row < NROWS; ++row) {
    int rr = rtop + row;
    const uint32_t* src =
        (rr >= 0 && rr < H) ? bits + ((size_t)(b * H + rr) * W) * WPC : nullptr;
    for (int t = threadIdx.x; t < XROW; t += 256) {
      uint32_t v = 0;
      if (src) {
        int q = t - WPC;  // interior words occupy [8, 8+448)
        if (q >= 0 && q < W * WPC) v = src[q];
      }
      xl[row * XROW + t] = v;
    }
  }
}

// XOR-popcount over the full 3x3 window (9 taps x 8 words), zero-padded input.
__device__ __forceinline__ int popc72(const uint32_t* x, const uint32_t (&wr)[NW]) {
  int a0 = 0, a1 = 0, a2 = 0, a3 = 0;
#pragma unroll
  for (int ky = 0; ky < 3; ++ky) {
    const uint32_t* xr = x + ky * XROW;
#pragma unroll
    for (int t = 0; t < 24; t += 4) {
      a0 += __popc(xr[t + 0] ^ wr[ky * 24 + t + 0]);
      a1 += __popc(xr[t + 1] ^ wr[ky * 24 + t + 1]);
      a2 += __popc(xr[t + 2] ^ wr[ky * 24 + t + 2]);
      a3 += __popc(xr[t + 3] ^ wr[ky * 24 + t + 3]);
    }
  }
  return (a0 + a1) + (a2 + a3);
}

// ---------------------------------------------------------------------------
// Conv1 (XNOR) + BN1 + sign -> packed bits.
__global__ __launch_bounds__(256) void k_conv1(const uint32_t* __restrict__ xbits,
                                               const uint32_t* __restrict__ wbT,
                                               const float* __restrict__ beta1,
                                               const float* __restrict__ mean1,
                                               const float* __restrict__ var1,
                                               uint32_t* __restrict__ hbits) {
  const int r = blockIdx.x;  // 0..55
  const int b = blockIdx.y;  // 0..31
  const int oc = threadIdx.x;

  __shared__ uint32_t xl[3 * XROW];
  stage_rows<3>(xbits, b, r - 1, xl);

  uint32_t wr[NW];
#pragma unroll
  for (int j = 0; j < NW; ++j) wr[j] = wbT[j * C + oc];

  int pw[9];
#pragma unroll
  for (int tp = 0; tp < 9; ++tp) {
    int s = 0;
#pragma unroll
    for (int w = 0; w < 8; ++w) s += __popc(wr[tp * 8 + w]);
    pw[tp] = s;
  }

  const bool rv0 = (r > 0), rv2 = (r < H - 1);
  auto calc_corr = [&](bool cvL, bool cvR) {
    int nv = 0, pv = 0;
#pragma unroll
    for (int ky = 0; ky < 3; ++ky) {
      bool rvk = (ky == 0) ? rv0 : ((ky == 2) ? rv2 : true);
#pragma unroll
      for (int kx = 0; kx < 3; ++kx) {
        bool cvk = (kx == 0) ? cvL : ((kx == 2) ? cvR : true);
        if (rvk && cvk) nv++; else pv += pw[ky * 3 + kx];
      }
    }
    return 256 * nv + 2 * pv;
  };
  const int corrI = calc_corr(true, true);
  const int corrL = calc_corr(false, true);
  const int corrR = calc_corr(true, false);

  // BN1 + sign threshold: bn >= 0  <=>  dot >= mean - beta*sqrt(var+eps)
  const float t1 = mean1[oc] - beta1[oc] * sqrtf(var1[oc] + BN_EPS);

  __syncthreads();

  unsigned long long* hrow =
      (unsigned long long*)hbits + ((size_t)(b * H + r) * W) * (WPC / 2);
  const int wv = oc >> 6;
  for (int c = 0; c < W; ++c) {
    int P = popc72(&xl[c * WPC], wr);
    int corr = (c == 0) ? corrL : ((c == W - 1) ? corrR : corrI);
    float dot = (float)(corr - 2 * P);
    unsigned long long m = __ballot(dot >= t1);
    if ((oc & 63) == 0) hrow[(size_t)c * 4 + wv] = m;
  }
}

// ---------------------------------------------------------------------------
// Conv2 (XNOR) + 2x2 maxpool + BN2 -> f32 output.
__global__ __launch_bounds__(256) void k_conv2(const uint32_t* __restrict__ hbits,
                                               const uint32_t* __restrict__ wbT,
                                               const float* __restrict__ beta2,
                                               const float* __restrict__ mean2,
                                               const float* __restrict__ var2,
                                               float* __restrict__ out) {
  const int ro = blockIdx.x;  // 0..27
  const int b = blockIdx.y;   // 0..31
  const int oc = threadIdx.x;

  __shared__ uint32_t xl[4 * XROW];
  stage_rows<4>(hbits, b, 2 * ro - 1, xl);

  uint32_t wr[NW];
#pragma unroll
  for (int j = 0; j < NW; ++j) wr[j] = wbT[j * C + oc];

  int pw[9];
#pragma unroll
  for (int tp = 0; tp < 9; ++tp) {
    int s = 0;
#pragma unroll
    for (int w = 0; w < 8; ++w) s += __popc(wr[tp * 8 + w]);
    pw[tp] = s;
  }

  const bool rvA0 = (ro > 0);       // dr=0 window top row valid
  const bool rvB2 = (ro < HO - 1);  // dr=1 window bottom row valid
  auto calc_corr = [&](bool rv0, bool rv2, bool cvL, bool cvR) {
    int nv = 0, pv = 0;
#pragma unroll
    for (int ky = 0; ky < 3; ++ky) {
      bool rvk = (ky == 0) ? rv0 : ((ky == 2) ? rv2 : true);
#pragma unroll
      for (int kx = 0; kx < 3; ++kx) {
        bool cvk = (kx == 0) ? cvL : ((kx == 2) ? cvR : true);
        if (rvk && cvk) nv++; else pv += pw[ky * 3 + kx];
      }
    }
    return 256 * nv + 2 * pv;
  };
  const int cA_I = calc_corr(rvA0, true, true, true);
  const int cA_L = calc_corr(rvA0, true, false, true);
  const int cA_R = calc_corr(rvA0, true, true, false);
  const int cB_I = calc_corr(true, rvB2, true, true);
  const int cB_L = calc_corr(true, rvB2, false, true);
  const int cB_R = calc_corr(true, rvB2, true, false);

  const float s2 = rsqrtf(var2[oc] + BN_EPS);
  const float mu2 = mean2[oc];
  const float be2 = beta2[oc];

  __syncthreads();

  float* orow = out + ((size_t)(b * HO + ro) * WO) * C + oc;
  for (int co = 0; co < WO; ++co) {
    int cL = 2 * co, cR = 2 * co + 1;
    int P00 = popc72(&xl[cL * WPC], wr);
    int P01 = popc72(&xl[cR * WPC], wr);
    int P10 = popc72(&xl[XROW + cL * WPC], wr);
    int P11 = popc72(&xl[XROW + cR * WPC], wr);
    int d00 = ((co == 0) ? cA_L : cA_I) - 2 * P00;
    int d01 = ((co == WO - 1) ? cA_R : cA_I) - 2 * P01;
    int d10 = ((co == 0) ? cB_L : cB_I) - 2 * P10;
    int d11 = ((co == WO - 1) ? cB_R : cB_I) - 2 * P11;
    int mx = max(max(d00, d01), max(d10, d11));
    orow[(size_t)co * C] = ((float)mx - mu2) * s2 + be2;
  }
}

// ---------------------------------------------------------------------------
extern "C" void kernel_launch(void* const* d_in, const int* in_sizes, int n_in,
                              void* d_out, int out_size, void* d_ws, size_t ws_size,
                              hipStream_t stream) {
  const float* x     = (const float*)d_in[0];
  const float* w1    = (const float*)d_in[1];
  const float* beta1 = (const float*)d_in[2];
  const float* mean1 = (const float*)d_in[3];
  const float* var1  = (const float*)d_in[4];
  const float* w2    = (const float*)d_in[5];
  const float* beta2 = (const float*)d_in[6];
  const float* mean2 = (const float*)d_in[7];
  const float* var2  = (const float*)d_in[8];
  float* out = (float*)d_out;

  uint32_t* ws32 = (uint32_t*)d_ws;
  const size_t XBW = (size_t)B * H * W * WPC;  // 802816 u32
  uint32_t* xbits = ws32;
  uint32_t* hbits = ws32 + XBW;
  uint32_t* wb1   = ws32 + 2 * XBW;
  uint32_t* wb2   = wb1 + NW * C;

  k_binarize_x<<<dim3((B * H * W * C) / 256), 256, 0, stream>>>(x, xbits);
  k_binarize_w<<<dim3(NW), 256, 0, stream>>>(w1, wb1);
  k_binarize_w<<<dim3(NW), 256, 0, stream>>>(w2, wb2);
  k_conv1<<<dim3(H, B), 256, 0, stream>>>(xbits, wb1, beta1, mean1, var1, hbits);
  k_conv2<<<dim3(HO, B), 256, 0, stream>>>(hbits, wb2, beta2, mean2, var2, out);
}

// Round 2
// 318.065 us; speedup vs baseline: 4.6345x; 4.6345x over previous
//
#include <hip/hip_runtime.h>
#include <stdint.h>

#define BN_EPS 1e-3f

constexpr int Bn = 32, H = 56, W = 56, C = 256;
constexpr int WPC = 8;            // u32 words per 256-channel bit vector
constexpr int HO = 28, WO = 28;   // pooled output dims
constexpr int NW = 72;            // 9 taps * 8 words

// ---------------------------------------------------------------------------
// Binarize x: bit c = (x >= 0). Pack via wave ballot.
__global__ __launch_bounds__(256) void k_binarize_x(const float* __restrict__ x,
                                                    uint32_t* __restrict__ xbits) {
  int i = blockIdx.x * 256 + threadIdx.x;
  float v = x[i];
  unsigned long long m = __ballot(v >= 0.0f);
  if ((threadIdx.x & 63) == 0) {
    ((unsigned long long*)xbits)[i >> 6] = m;
  }
}

// ---------------------------------------------------------------------------
// Binarize weights HWIO [3][3][256 ic][256 oc] -> wbT[oc][j], j = tap*8+word,
// bit b of word = ic = word*32+b.  (oc-major so conv loads are wave-uniform.)
__global__ __launch_bounds__(256) void k_binarize_w(const float* __restrict__ w,
                                                    uint32_t* __restrict__ wbT) {
  int j = blockIdx.x;        // 0..71
  int oc = threadIdx.x;      // 0..255
  int tap = j >> 3, ww = j & 7;
  const float* base = w + ((size_t)(tap * C) + ww * 32) * C + oc;
  uint32_t bits = 0;
#pragma unroll
  for (int b = 0; b < 32; ++b) {
    float v = base[(size_t)b * C];
    bits |= (v >= 0.0f ? 1u : 0u) << b;
  }
  wbT[(size_t)oc * NW + j] = bits;
}

// ---------------------------------------------------------------------------
// Padding-correction scalars. For zero-filled invalid taps:
//   dot = corr - 2*P_total,  corr = 256*n_valid + 2*sum_invalid popc(w_tap)
__device__ __forceinline__ void corr3(const int* pw, bool rv0, bool rv2,
                                      int& cI, int& cL, int& cR) {
  int nvI = 0, pvI = 0, nvL = 0, pvL = 0, nvR = 0, pvR = 0;
#pragma unroll
  for (int ky = 0; ky < 3; ++ky) {
    bool rvk = (ky == 0) ? rv0 : ((ky == 2) ? rv2 : true);
#pragma unroll
    for (int kx = 0; kx < 3; ++kx) {
      int p = pw[ky * 3 + kx];
      if (rvk) nvI++; else pvI += p;
      if (rvk && kx != 0) nvL++; else pvL += p;
      if (rvk && kx != 2) nvR++; else pvR += p;
    }
  }
  cI = 256 * nvI + 2 * pvI;
  cL = 256 * nvL + 2 * pvL;
  cR = 256 * nvR + 2 * pvR;
}

// Per-oc tables: ct[oc][0..2]=I,L,R for (rv0=1,rv2=1); [3..5] for (0,1);
// [6..8] for (1,0); [9] = sub0 = popc of all kx=0 weights (virtual col -1).
__global__ __launch_bounds__(256) void k_prep(
    const uint32_t* __restrict__ wb1, const uint32_t* __restrict__ wb2,
    const float* __restrict__ beta1, const float* __restrict__ mean1,
    const float* __restrict__ var1, const float* __restrict__ beta2,
    const float* __restrict__ mean2, const float* __restrict__ var2,
    int* __restrict__ ct1, int* __restrict__ ct2, float* __restrict__ thr1,
    float* __restrict__ a2t, float* __restrict__ b2t) {
  int oc = threadIdx.x;
#pragma unroll
  for (int s = 0; s < 2; ++s) {
    const uint32_t* wb = s ? wb2 : wb1;
    int* ct = (s ? ct2 : ct1) + oc * 10;
    int pw[9];
#pragma unroll
    for (int t = 0; t < 9; ++t) {
      int acc = 0;
#pragma unroll
      for (int w = 0; w < 8; ++w) acc += __popc(wb[(size_t)oc * NW + t * 8 + w]);
      pw[t] = acc;
    }
    corr3(pw, true, true, ct[0], ct[1], ct[2]);
    corr3(pw, false, true, ct[3], ct[4], ct[5]);
    corr3(pw, true, false, ct[6], ct[7], ct[8]);
    ct[9] = pw[0] + pw[3] + pw[6];
  }
  thr1[oc] = mean1[oc] - beta1[oc] * sqrtf(var1[oc] + BN_EPS);
  float s2 = rsqrtf(var2[oc] + BN_EPS);
  a2t[oc] = s2;
  b2t[oc] = beta2[oc] - mean2[oc] * s2;
}

// ---------------------------------------------------------------------------
// Per-lane row load: lane owns one column's 8 bit-words; zeros outside.
__device__ __forceinline__ void load_row(const uint32_t* __restrict__ bits, int b,
                                         int rr, int c, uint32_t* X) {
  if (rr >= 0 && rr < H && c < W) {
    const uint32_t* p = bits + (((size_t)b * H + rr) * W + c) * WPC;
    uint4 a = *(const uint4*)p;
    uint4 d = *(const uint4*)(p + 4);
    X[0] = a.x; X[1] = a.y; X[2] = a.z; X[3] = a.w;
    X[4] = d.x; X[5] = d.y; X[6] = d.z; X[7] = d.w;
  } else {
#pragma unroll
    for (int k = 0; k < 8; ++k) X[k] = 0;
  }
}

// Shared inner body: per-kx partial popcounts for two adjacent output rows.
#define QBODY(wp)                                                         \
  int q0A = 0, q1A = 0, q2A = 0, q0B = 0, q1B = 0, q2B = 0;               \
  _Pragma("unroll") for (int ky = 0; ky < 3; ++ky) {                      \
    _Pragma("unroll") for (int w = 0; w < 8; ++w) {                       \
      const uint32_t w0 = (wp)[ky * 24 + w];                              \
      const uint32_t w1 = (wp)[ky * 24 + 8 + w];                          \
      const uint32_t w2 = (wp)[ky * 24 + 16 + w];                         \
      const uint32_t xA = X[ky][w], xB = X[ky + 1][w];                    \
      q0A += __popc(xA ^ w0); q1A += __popc(xA ^ w1);                     \
      q2A += __popc(xA ^ w2);                                             \
      q0B += __popc(xB ^ w0); q1B += __popc(xB ^ w1);                     \
      q2B += __popc(xB ^ w2);                                             \
    }                                                                     \
  }                                                                       \
  int u0A = __shfl_up(q0A, 1), u0B = __shfl_up(q0B, 1);                   \
  int d2A = __shfl_down(q2A, 1), d2B = __shfl_down(q2B, 1);               \
  if (lane == 0) { u0A = sub0; u0B = sub0; }                              \
  const int PA = u0A + q1A + d2A;                                         \
  const int PB = u0B + q1B + d2B;                                         \
  const int corrA = (lane == 0) ? cAL : ((lane == W - 1) ? cAR : cAI);    \
  const int corrB = (lane == 0) ? cBL : ((lane == W - 1) ? cBR : cBI);

// ---------------------------------------------------------------------------
// Conv1 (XNOR) + BN1 + sign -> packed bits. Wave = one row pair, 32 oc.
__global__ __launch_bounds__(256) void k_conv1(
    const uint32_t* __restrict__ xbits, const uint32_t* __restrict__ wbT,
    const int* __restrict__ ctab, const float* __restrict__ thr1,
    uint32_t* __restrict__ hbits) {
  const int lane = threadIdx.x & 63;
  const int q = __builtin_amdgcn_readfirstlane(blockIdx.x * 4 + (threadIdx.x >> 6));
  const int b = blockIdx.y;
  const int ocbase = blockIdx.z * 32;
  const int rA = 2 * q, rB = rA + 1;
  const int c = lane;

  uint32_t X[4][8];
#pragma unroll
  for (int i = 0; i < 4; ++i) load_row(xbits, b, rA - 1 + i, c, X[i]);

  const bool rvA0 = (q > 0), rvB2 = (q < 27);
  uint32_t bitsA = 0, bitsB = 0;

  for (int oc = ocbase; oc < ocbase + 32; ++oc) {
    const uint32_t* wp = wbT + (size_t)oc * NW;
    const int* ct = ctab + oc * 10;
    const int cAI = rvA0 ? ct[0] : ct[3];
    const int cAL = rvA0 ? ct[1] : ct[4];
    const int cAR = rvA0 ? ct[2] : ct[5];
    const int cBI = rvB2 ? ct[0] : ct[6];
    const int cBL = rvB2 ? ct[1] : ct[7];
    const int cBR = rvB2 ? ct[2] : ct[8];
    const int sub0 = ct[9];
    const float t1 = thr1[oc];

    QBODY(wp)

    const uint32_t sh = (uint32_t)(oc - ocbase);
    bitsA |= (uint32_t)(((float)(corrA - 2 * PA) >= t1) ? 1u : 0u) << sh;
    bitsB |= (uint32_t)(((float)(corrB - 2 * PB) >= t1) ? 1u : 0u) << sh;
  }
  if (c < W) {
    const int wd = ocbase >> 5;
    hbits[(((size_t)b * H + rA) * W + c) * WPC + wd] = bitsA;
    hbits[(((size_t)b * H + rB) * W + c) * WPC + wd] = bitsB;
  }
}

// ---------------------------------------------------------------------------
// Conv2 (XNOR) + 2x2 maxpool + BN2 -> f32. Wave = one pooled row, 32 oc.
__global__ __launch_bounds__(256) void k_conv2(
    const uint32_t* __restrict__ hbits, const uint32_t* __restrict__ wbT,
    const int* __restrict__ ctab, const float* __restrict__ a2t,
    const float* __restrict__ b2t, float* __restrict__ out) {
  const int lane = threadIdx.x & 63;
  const int ro = __builtin_amdgcn_readfirstlane(blockIdx.x * 4 + (threadIdx.x >> 6));
  const int b = blockIdx.y;
  const int ocbase = blockIdx.z * 32;
  const int rA = 2 * ro;
  const int c = lane;

  uint32_t X[4][8];
#pragma unroll
  for (int i = 0; i < 4; ++i) load_row(hbits, b, rA - 1 + i, c, X[i]);

  const bool rvA0 = (ro > 0), rvB2 = (ro < 27);
  const bool writer = ((lane & 1) == 0) && (lane < W);
  float* orow = out + (((size_t)b * HO + ro) * WO + (lane >> 1)) * C;

  for (int oc4 = ocbase; oc4 < ocbase + 32; oc4 += 4) {
    float o0, o1, o2, o3;
#pragma unroll
    for (int k = 0; k < 4; ++k) {
      const int oc = oc4 + k;
      const uint32_t* wp = wbT + (size_t)oc * NW;
      const int* ct = ctab + oc * 10;
      const int cAI = rvA0 ? ct[0] : ct[3];
      const int cAL = rvA0 ? ct[1] : ct[4];
      const int cAR = rvA0 ? ct[2] : ct[5];
      const int cBI = rvB2 ? ct[0] : ct[6];
      const int cBL = rvB2 ? ct[1] : ct[7];
      const int cBR = rvB2 ? ct[2] : ct[8];
      const int sub0 = ct[9];

      QBODY(wp)

      const int dotA = corrA - 2 * PA;
      const int dotB = corrB - 2 * PB;
      int t = max(dotA, dotB);
      int m = max(t, __shfl_xor(t, 1));
      float val = (float)m * a2t[oc] + b2t[oc];
      if (k == 0) o0 = val; else if (k == 1) o1 = val;
      else if (k == 2) o2 = val; else o3 = val;
    }
    if (writer) {
      float4 v = make_float4(o0, o1, o2, o3);
      *(float4*)(orow + oc4) = v;
    }
  }
}

// ---------------------------------------------------------------------------
extern "C" void kernel_launch(void* const* d_in, const int* in_sizes, int n_in,
                              void* d_out, int out_size, void* d_ws, size_t ws_size,
                              hipStream_t stream) {
  const float* x     = (const float*)d_in[0];
  const float* w1    = (const float*)d_in[1];
  const float* beta1 = (const float*)d_in[2];
  const float* mean1 = (const float*)d_in[3];
  const float* var1  = (const float*)d_in[4];
  const float* w2    = (const float*)d_in[5];
  const float* beta2 = (const float*)d_in[6];
  const float* mean2 = (const float*)d_in[7];
  const float* var2  = (const float*)d_in[8];
  float* out = (float*)d_out;

  uint32_t* ws32 = (uint32_t*)d_ws;
  const size_t XBW = (size_t)Bn * H * W * WPC;  // 802816 u32
  uint32_t* xbits = ws32;
  uint32_t* hbits = xbits + XBW;
  uint32_t* wb1   = hbits + XBW;
  uint32_t* wb2   = wb1 + (size_t)C * NW;
  int* ct1        = (int*)(wb2 + (size_t)C * NW);
  int* ct2        = ct1 + C * 10;
  float* thr1     = (float*)(ct2 + C * 10);
  float* a2t      = thr1 + C;
  float* b2t      = a2t + C;

  k_binarize_x<<<dim3((Bn * H * W * C) / 256), 256, 0, stream>>>(x, xbits);
  k_binarize_w<<<dim3(NW), 256, 0, stream>>>(w1, wb1);
  k_binarize_w<<<dim3(NW), 256, 0, stream>>>(w2, wb2);
  k_prep<<<dim3(1), 256, 0, stream>>>(wb1, wb2, beta1, mean1, var1,
                                      beta2, mean2, var2, ct1, ct2, thr1, a2t, b2t);
  k_conv1<<<dim3(7, Bn, 8), 256, 0, stream>>>(xbits, wb1, ct1, thr1, hbits);
  k_conv2<<<dim3(7, Bn, 8), 256, 0, stream>>>(hbits, wb2, ct2, a2t, b2t, out);
}